// Round 2
// baseline (2649.120 us; speedup 1.0000x reference)
//
#include <hip/hip_runtime.h>
#include <hip/hip_bf16.h>

// LSTM decoder B=256, T=512, H=1024 — persistent fp16 MFMA, v9.
// v8 (2542 us measured) repartitioned: waves = (m-half x nt-half x K-half).
// Each wave owns ALL 4 gates of one 16x16 (m,j) tile over half of K:
//  - split-K 4->2: one LDS exchange round (conflict-free contiguous b128),
//    ONE sync instead of three.
//  - epilogue fully in-register (all 4 gates of a cell live in one lane);
//    removes the 4-way-conflicted scr reads (1.09e8 conflict cycles in v8).
//  - h store via 2KB XOR-swizzled LDS bounce; global store path identical
//    to v8 (coalesced u32 sc0sc1 full 256B lines).
// Barrier: v6 monolithic m-group counter (proven).

#define BB 256
#define TT 512
#define HH 1024

typedef __attribute__((ext_vector_type(8))) short short8;
typedef __attribute__((ext_vector_type(8))) _Float16 half8;
typedef __attribute__((ext_vector_type(4))) float float4v;

#define HP_U64 ((size_t)65536)   // u64 per h buffer: 256 U-units x 256 rows

__device__ __forceinline__ float sigf(float x) { return 1.0f / (1.0f + __expf(-x)); }
__device__ __forceinline__ float tanhff(float x) {
    return 1.0f - 2.0f / (__expf(2.0f * x) + 1.0f);
}

// ---- pack W_hh (4096x1024 f32) -> fp16 B-fragment order ----
// Wp[jt2(32)][kc(32)][g(4)][nt(2)][lane(64)][8] ; per-jt2 block = 256 KB
__global__ __launch_bounds__(256) void pack_w(const float* __restrict__ W_hh,
                                              unsigned short* __restrict__ Wp) {
    int fid = blockIdx.x * 256 + threadIdx.x;   // 0..524287
    int lane = fid & 63;
    int nt = (fid >> 6) & 1;
    int g = (fid >> 7) & 3;
    int kc = (fid >> 9) & 31;
    int jt2 = fid >> 14;
    int j = jt2 * 32 + nt * 16 + (lane & 15);
    int row = g * HH + j;
    int k = kc * 32 + (lane >> 4) * 8;
    const float* src = W_hh + (size_t)row * HH + k;
    union { _Float16 h[8]; short8 s; } u;
#pragma unroll
    for (int e = 0; e < 8; ++e) u.h[e] = (_Float16)src[e];
    *(short8*)(Wp + (size_t)fid * 8) = u.s;
}

// ---- h0 -> fp16 fragment layout in buffer 0; zero barrier counters ----
// unit U=(k>>5)*8+((k>>2)&7); u64 idx = U*256 + M  (boff == M)
__global__ __launch_bounds__(256) void prep_state(const float* __restrict__ h0,
                                                  unsigned long long* __restrict__ hb0,
                                                  unsigned int* __restrict__ cnt) {
    int gid = blockIdx.x * 256 + threadIdx.x;   // 0..65535
    int r = gid & 255;
    int U = gid >> 8;
    int kb = (U >> 3) * 32 + ((U >> 1) & 3) * 8 + (U & 1) * 4;
    float4 v = *(const float4*)(h0 + (size_t)r * HH + kb);
    union { _Float16 h[4]; unsigned long long u; } x;
    x.h[0] = (_Float16)v.x; x.h[1] = (_Float16)v.y;
    x.h[2] = (_Float16)v.z; x.h[3] = (_Float16)v.w;
    hb0[(size_t)U * 256 + r] = x.u;
    if (blockIdx.x == 0) cnt[threadIdx.x] = 0;   // 256 u32 = 8 groups x 32
}

// ---- persistent LSTM kernel: all 512 steps + final FC ----
__global__ __launch_bounds__(512, 1) void lstm_persist(
    const float* __restrict__ y_hist,
    const float* __restrict__ W_ih,           // (4096) flat
    const float* __restrict__ b_ih,
    const float* __restrict__ b_hh,
    const float* __restrict__ c0,             // (B,H) f32
    const float* __restrict__ W_fc,           // (H)
    const float* __restrict__ b_fc,           // (1)
    const unsigned short* __restrict__ Wp,    // packed fp16 W fragments
    unsigned long long* hbase,                // 2 buffers x HP_U64 u64
    unsigned int* cnt,
    float* __restrict__ out)
{
    __shared__ __align__(16) unsigned short Wlds[65536];   // 128 KB: gates 0,1
    __shared__ __align__(16) float excf[4096];             // 16 KB: split-K exchange
    __shared__ __align__(8)  unsigned short hexb[1024];    // 2 KB: h store bounce
    // 146 KiB -> 1 WG/CU; grid=256 => all WGs co-resident

    const int tid = threadIdx.x;
    const int lane = tid & 63;
    const int wv = tid >> 6;
    const int nt = wv & 1;                     // j half (16 cols)
    const int m2 = (wv >> 1) & 1;              // m half (16 rows)
    const int kh = wv >> 2;                    // K half (512 k)
    const int bid = blockIdx.x;
    const int gm = bid >> 5;                   // m-group 0..7 (32 rows)
    const int jt2 = bid & 31;                  // 32-j tile

    const unsigned short* WpJ = Wp + (size_t)jt2 * 131072;

    // --- LDS: gates 0,1 fragments (all kc, both nt) ---
    for (int f = tid; f < 8192; f += 512) {
        int kc = f >> 8, g = (f >> 7) & 1, low = f & 127;
        *(short8*)&Wlds[(size_t)((kc * 2 + g) * 128 + low) * 8] =
            *(const short8*)(WpJ + (size_t)((kc * 4 + g) * 128 + low) * 8);
    }
    // --- registers: gates 2,3 fragments for this wave's (nt, K-half) ---
    half8 Breg[16][2];   // [kc_l][g-2]
#pragma unroll
    for (int kc_l = 0; kc_l < 16; ++kc_l) {
        int kc = kh * 16 + kc_l;
#pragma unroll
        for (int g2 = 0; g2 < 2; ++g2)
            Breg[kc_l][g2] = *(const half8*)
                (WpJ + (size_t)((((kc * 4 + 2 + g2) * 2 + nt) * 64 + lane)) * 8);
    }

    // --- A addressing ---
    const int blk = gm * 2 + m2;               // 16-row block 0..15
    const int q = lane >> 4;
    const size_t abase = (size_t)blk * 16 + (lane & 15);
    const size_t qoff = (size_t)q * 512;

    // --- epilogue per-lane constants: 2 cells = rows (mrow0, mrow0+1), col j ---
    const int j = jt2 * 32 + nt * 16 + (lane & 15);
    const int mrow0 = gm * 32 + m2 * 16 + (lane >> 4) * 4 + kh * 2;
    float wi_[4], bs_[4];
#pragma unroll
    for (int g = 0; g < 4; ++g) {
        wi_[g] = W_ih[g * HH + j];
        bs_[g] = b_ih[g * HH + j] + b_hh[g * HH + j];
    }
    float c_0 = c0[(size_t)mrow0 * HH + j];
    float c_1 = c0[(size_t)(mrow0 + 1) * HH + j];

    // --- h bounce LDS indices (XOR-swizzled; write u16, read u32) ---
    const int mlA = m2 * 16 + (lane >> 4) * 4 + kh * 2;   // WG-local row of cell 0
    const int jl = nt * 16 + (lane & 15);                 // WG-local col
    const int hw0 = (mlA * 16 + ((jl >> 1) ^ (mlA & 7))) * 2 + (jl & 1);
    const int hw1 = ((mlA + 1) * 16 + ((jl >> 1) ^ ((mlA + 1) & 7))) * 2 + (jl & 1);

    // --- store-phase mapping (identical to v8: full 256B lines per wave) ---
    const int em = tid & 31;                   // tile-local row
    const int jp = tid >> 5;                   // j-pair 0..15
    const int jq = jp >> 1;
    const int M = gm * 32 + em;
    const size_t sidx32 = ((size_t)(jt2 * 8 + jq) * 256 + M) * 2 + (jp & 1);
    const int rdw = em * 16 + (jp ^ (em & 7)); // u32 word idx in hexb

    __syncthreads();   // Wlds visible

    unsigned int* mycnt = cnt + gm * 32;

    for (int t = 0; t < TT; ++t) {
        const unsigned long long* hR = hbase + (size_t)(t & 1) * HP_U64;
        unsigned long long* hW = hbase + (size_t)((t + 1) & 1) * HP_U64;

        // y_hist x for both cell rows (consumed in epilogue; hides under K-loop)
        float x0 = y_hist[(size_t)mrow0 * TT + t];
        float x1 = y_hist[(size_t)(mrow0 + 1) * TT + t];

        float4v acc[4] = {{0.f,0.f,0.f,0.f},{0.f,0.f,0.f,0.f},
                          {0.f,0.f,0.f,0.f},{0.f,0.f,0.f,0.f}};

        // --- sync-free K-half loop: 16 chunks of K=32, full prefetch ring ---
        unsigned long long ring[16][2];
#pragma unroll
        for (int p = 0; p < 16; ++p) {
            size_t ua = (size_t)(kh * 16 + p) * 2048 + qoff + abase;
            ring[p][0] = __hip_atomic_load((unsigned long long*)&hR[ua],
                                           __ATOMIC_RELAXED, __HIP_MEMORY_SCOPE_AGENT);
            ring[p][1] = __hip_atomic_load((unsigned long long*)&hR[ua + 256],
                                           __ATOMIC_RELAXED, __HIP_MEMORY_SCOPE_AGENT);
        }
#pragma unroll
        for (int ch = 0; ch < 16; ++ch) {
            union { unsigned long long u[2]; half8 h; } af;
            af.u[0] = ring[ch][0];
            af.u[1] = ring[ch][1];
            const int kc = kh * 16 + ch;
#pragma unroll
            for (int g = 0; g < 2; ++g) {
                half8 bh = *(const half8*)
                    &Wlds[(size_t)((kc * 2 + g) * 128 + nt * 64 + lane) * 8];
                acc[g] =
                    __builtin_amdgcn_mfma_f32_16x16x32_f16(af.h, bh, acc[g], 0, 0, 0);
            }
#pragma unroll
            for (int g2 = 0; g2 < 2; ++g2)
                acc[2 + g2] =
                    __builtin_amdgcn_mfma_f32_16x16x32_f16(af.h, Breg[ch][g2],
                                                           acc[2 + g2], 0, 0, 0);
        }

        // --- 2-way split-K exchange: keep rows kh*2+{0,1}, send the others.
        //     Static indexing only (wave-uniform branch), rule #20. ---
        float k0[4], k1[4];
        float4v s0, s1;
        if (kh == 0) {
#pragma unroll
            for (int g = 0; g < 4; ++g) {
                k0[g] = acc[g][0]; k1[g] = acc[g][1];
                s0[g] = acc[g][2]; s1[g] = acc[g][3];
            }
        } else {
#pragma unroll
            for (int g = 0; g < 4; ++g) {
                k0[g] = acc[g][2]; k1[g] = acc[g][3];
                s0[g] = acc[g][0]; s1[g] = acc[g][1];
            }
        }
        // contiguous stride-16B b128 writes: conflict-free
        *(float4v*)&excf[wv * 512 + lane * 4] = s0;
        *(float4v*)&excf[wv * 512 + 256 + lane * 4] = s1;
        __syncthreads();
        float4v p0 = *(const float4v*)&excf[(wv ^ 4) * 512 + lane * 4];
        float4v p1 = *(const float4v*)&excf[(wv ^ 4) * 512 + 256 + lane * 4];

        // --- epilogue fully in-register: 2 cells (rows mrow0, mrow0+1) ---
        {
            float gi = k0[0] + p0[0] + x0 * wi_[0] + bs_[0];
            float gf = k0[1] + p0[1] + x0 * wi_[1] + bs_[1];
            float gg = k0[2] + p0[2] + x0 * wi_[2] + bs_[2];
            float go = k0[3] + p0[3] + x0 * wi_[3] + bs_[3];
            float cn = sigf(gf) * c_0 + sigf(gi) * tanhff(gg);
            c_0 = cn;
            union { _Float16 h; unsigned short s; } cv;
            cv.h = (_Float16)(sigf(go) * tanhff(cn));
            hexb[hw0] = cv.s;
        }
        {
            float gi = k1[0] + p1[0] + x1 * wi_[0] + bs_[0];
            float gf = k1[1] + p1[1] + x1 * wi_[1] + bs_[1];
            float gg = k1[2] + p1[2] + x1 * wi_[2] + bs_[2];
            float go = k1[3] + p1[3] + x1 * wi_[3] + bs_[3];
            float cn = sigf(gf) * c_1 + sigf(gi) * tanhff(gg);
            c_1 = cn;
            union { _Float16 h; unsigned short s; } cv;
            cv.h = (_Float16)(sigf(go) * tanhff(cn));
            hexb[hw1] = cv.s;
        }
        __syncthreads();

        // --- coalesced u32 store (identical pattern to v8) ---
        unsigned int hvu = *(const unsigned int*)&hexb[(size_t)rdw * 2];
        asm volatile("global_store_dword %0, %1, off sc0 sc1"
                     : : "v"((void*)((unsigned int*)hW + sidx32)), "v"(hvu) : "memory");

        // --- drain stores, then m-group barrier (32 WGs, proven) ---
        asm volatile("s_waitcnt vmcnt(0)" ::: "memory");
        __syncthreads();
        if (tid == 0) {
            __hip_atomic_fetch_add(mycnt, 1u, __ATOMIC_RELAXED, __HIP_MEMORY_SCOPE_AGENT);
            unsigned target = 32u * (unsigned)(t + 1);
            while (__hip_atomic_load(mycnt, __ATOMIC_RELAXED, __HIP_MEMORY_SCOPE_AGENT) <
                   target)
                __builtin_amdgcn_s_sleep(1);
        }
        __syncthreads();
    }

    // --- final FC (h final in buffer 0): jt2==0 WGs, kh==0/nt==0 waves ---
    if (jt2 == 0 && kh == 0 && nt == 0) {
        const unsigned long long* hF = hbase;   // buffer 0
#pragma unroll 1
        for (int rr = 0; rr < 16; ++rr) {
            int row = gm * 32 + m2 * 16 + rr;
            int boff = row;                     // boff == M
            float s = 0.f;
#pragma unroll 1
            for (int uu = 0; uu < 4; ++uu) {
                int U = uu * 64 + lane;
                unsigned long long u = __hip_atomic_load(
                    (unsigned long long*)&hF[(size_t)U * 256 + boff],
                    __ATOMIC_RELAXED, __HIP_MEMORY_SCOPE_AGENT);
                int kb = (U >> 3) * 32 + ((U >> 1) & 3) * 8 + (U & 1) * 4;
                union { _Float16 h[4]; unsigned long long x; } v;
                v.x = u;
                float4 wf = *(const float4*)(W_fc + kb);
                s += (float)v.h[0] * wf.x + (float)v.h[1] * wf.y +
                     (float)v.h[2] * wf.z + (float)v.h[3] * wf.w;
            }
#pragma unroll
            for (int off = 32; off > 0; off >>= 1) s += __shfl_xor(s, off);
            if (lane == 0) out[row] = s + b_fc[0];
        }
    }
}

extern "C" void kernel_launch(void* const* d_in, const int* in_sizes, int n_in,
                              void* d_out, int out_size, void* d_ws, size_t ws_size,
                              hipStream_t stream) {
    const float* y_hist = (const float*)d_in[0];
    const float* W_ih   = (const float*)d_in[1];
    const float* W_hh   = (const float*)d_in[2];
    const float* b_ih   = (const float*)d_in[3];
    const float* b_hh   = (const float*)d_in[4];
    const float* W_fc   = (const float*)d_in[5];
    const float* b_fc   = (const float*)d_in[6];
    const float* h0     = (const float*)d_in[7];
    const float* c0     = (const float*)d_in[8];
    float* out = (float*)d_out;

    // ws: Wp fp16 (8 MB) | h buffers 2 x 512 KB | cnt (1 KB)
    unsigned short* Wp = (unsigned short*)d_ws;
    unsigned long long* hbase = (unsigned long long*)(Wp + (size_t)4194304);
    unsigned int* cnt = (unsigned int*)(hbase + 2 * HP_U64);

    pack_w<<<2048, 256, 0, stream>>>(W_hh, Wp);
    prep_state<<<256, 256, 0, stream>>>(h0, hbase, cnt);

    // 256 WGs x 512 threads, 146 KiB LDS -> 1 WG/CU, all co-resident
    lstm_persist<<<256, 512, 0, stream>>>(y_hist, W_ih, b_ih, b_hh, c0, W_fc, b_fc,
                                          Wp, hbase, cnt, out);
}

// Round 6
// 2364.959 us; speedup vs baseline: 1.1202x; 1.1202x over previous
//
#include <hip/hip_runtime.h>
#include <hip/hip_bf16.h>
#include <type_traits>

// LSTM decoder B=256, T=512, H=1024 — persistent fp16 MFMA, v10.3.
// = v10.2 (XCD-local fast path, untested: 2 infra-failure rounds) made
// HANG-PROOF: all spin loops draw from a shared spin budget (~1M iters,
// 20-50x healthy usage). If a barrier genuinely stalls the budget empties,
// barriers degrade to non-blocking, kernel finishes with garbage ->
// passed=false diagnostic instead of a container kill. Detection bailout
// forces the SAFE (v8-identical) path.
// Theory (from R2, untested): h stores/loads + m-group barrier are
// XCD-L2-local when gm = bid & 7 puts each m-group on ONE XCD (round-robin
// dispatch, runtime-verified via HW_REG_XCC_ID mask; non-uniform -> v8 path).
// v8 evidence: WRITE_SIZE=266MB (every h store hits HBM), 63% step wait.
// Fastmode: stores sc0-only (vmcnt clears at XCD-L2 ack), loads sc1
// (device scope; probes same L2, hits dirty line - no stale-L1 hazard).

#define BB 256
#define TT 512
#define HH 1024

typedef __attribute__((ext_vector_type(8))) short short8;
typedef __attribute__((ext_vector_type(8))) _Float16 half8;
typedef __attribute__((ext_vector_type(4))) float float4v;

#define HP_U64 ((size_t)65536)   // u64 per h buffer: 256 U-units x 256 rows

__device__ __forceinline__ float sigf(float x) { return 1.0f / (1.0f + __expf(-x)); }
__device__ __forceinline__ float tanhff(float x) {
    return 1.0f - 2.0f / (__expf(2.0f * x) + 1.0f);
}

// ---- pack W_hh (4096x1024 f32) -> fp16 B-fragment order ----
// Wp[jt2(32)][kc(32)][g(4)][nt(2)][lane(64)][8] ; per-jt2 block = 256 KB
__global__ __launch_bounds__(256) void pack_w(const float* __restrict__ W_hh,
                                              unsigned short* __restrict__ Wp) {
    int fid = blockIdx.x * 256 + threadIdx.x;   // 0..524287
    int lane = fid & 63;
    int nt = (fid >> 6) & 1;
    int g = (fid >> 7) & 3;
    int kc = (fid >> 9) & 31;
    int jt2 = fid >> 14;
    int j = jt2 * 32 + nt * 16 + (lane & 15);
    int row = g * HH + j;
    int k = kc * 32 + (lane >> 4) * 8;
    const float* src = W_hh + (size_t)row * HH + k;
    union { _Float16 h[8]; short8 s; } u;
#pragma unroll
    for (int e = 0; e < 8; ++e) u.h[e] = (_Float16)src[e];
    *(short8*)(Wp + (size_t)fid * 8) = u.s;
}

// ---- h0 -> fp16 fragment layout in buffer 0; zero barrier counters ----
// unit U=(k>>5)*8+((k>>2)&7); u64 idx = U*256 + M  (boff == M)
__global__ __launch_bounds__(256) void prep_state(const float* __restrict__ h0,
                                                  unsigned long long* __restrict__ hb0,
                                                  unsigned int* __restrict__ cnt) {
    int gid = blockIdx.x * 256 + threadIdx.x;   // 0..65535
    int r = gid & 255;
    int U = gid >> 8;
    int kb = (U >> 3) * 32 + ((U >> 1) & 3) * 8 + (U & 1) * 4;
    float4 v = *(const float4*)(h0 + (size_t)r * HH + kb);
    union { _Float16 h[4]; unsigned long long u; } x;
    x.h[0] = (_Float16)v.x; x.h[1] = (_Float16)v.y;
    x.h[2] = (_Float16)v.z; x.h[3] = (_Float16)v.w;
    hb0[(size_t)U * 256 + r] = x.u;
    if (blockIdx.x == 0) cnt[threadIdx.x] = 0;   // 256 u32: per-group {bar, mask, arrive}
}

// ---- persistent LSTM kernel: all 512 steps + final FC ----
__global__ __launch_bounds__(512, 1) void lstm_persist(
    const float* __restrict__ y_hist,
    const float* __restrict__ W_ih,           // (4096) flat
    const float* __restrict__ b_ih,
    const float* __restrict__ b_hh,
    const float* __restrict__ c0,             // (B,H) f32
    const float* __restrict__ W_fc,           // (H)
    const float* __restrict__ b_fc,           // (1)
    const unsigned short* __restrict__ Wp,    // packed fp16 W fragments
    unsigned long long* hbase,                // 2 buffers x HP_U64 u64
    unsigned int* cnt,
    float* __restrict__ out)
{
    __shared__ __align__(16) unsigned short Wlds[65536];   // 128 KB: gates 0,1
    __shared__ __align__(16) float scr[8192];              // 32 KB: 4 regions x 2048
    // 160 KiB exactly -> 1 WG/CU; grid=256 => all WGs co-resident
    // (mode flag bounced through scr[0]; NO extra __shared__)

    const int tid = threadIdx.x;
    const int lane = tid & 63;
    const int wv = tid >> 6;
    const int m2 = wv & 1;                     // m half (16 rows)
    const int k4 = wv >> 1;                    // K quarter (256 k)
    const int bid = blockIdx.x;
    const int gm = bid & 7;                    // m-group == XCD id under round-robin
    const int jt2 = bid >> 3;                  // 32-j tile

    const unsigned short* WpJ = Wp + (size_t)jt2 * 131072;

    // --- LDS: gates 0,1 fragments (all kc) ---
    for (int f = tid; f < 8192; f += 512) {
        int kc = f >> 8, g = (f >> 7) & 1, low = f & 127;
        *(short8*)&Wlds[(size_t)((kc * 2 + g) * 128 + low) * 8] =
            *(const short8*)(WpJ + (size_t)((kc * 4 + g) * 128 + low) * 8);
    }
    // --- registers: gates 2,3 fragments for this wave's K-quarter ---
    half8 Breg[8][2][2];   // [kc_l][g-2][nt]
#pragma unroll
    for (int kc_l = 0; kc_l < 8; ++kc_l) {
        int kc = k4 * 8 + kc_l;
#pragma unroll
        for (int g2 = 0; g2 < 2; ++g2)
#pragma unroll
            for (int nt = 0; nt < 2; ++nt)
                Breg[kc_l][g2][nt] = *(const half8*)
                    (WpJ + (size_t)((((kc * 4 + 2 + g2) * 2 + nt) * 64 + lane)) * 8);
    }

    // --- A addressing ---
    const int blk = gm * 2 + m2;               // 16-row block 0..15
    const int q = lane >> 4;
    const size_t abase = (size_t)blk * 16 + (lane & 15);
    const size_t qoff = (size_t)q * 512;

    // --- epilogue constants (ALL 512 threads: cell = 1 row x 2 j) ---
    const int em = tid & 31;                   // tile-local row
    const int jp = tid >> 5;                   // j-pair 0..15
    const int jq = jp >> 1;
    const int M = gm * 32 + em;
    float wi_[4][2], bs_[4][2], c_[2];
#pragma unroll
    for (int g = 0; g < 4; ++g)
#pragma unroll
        for (int jj = 0; jj < 2; ++jj) {
            int j = jt2 * 32 + jp * 2 + jj;
            wi_[g][jj] = W_ih[g * HH + j];
            bs_[g][jj] = b_ih[g * HH + j] + b_hh[g * HH + j];
        }
#pragma unroll
    for (int jj = 0; jj < 2; ++jj)
        c_[jj] = c0[(size_t)M * HH + jt2 * 32 + jp * 2 + jj];
    // u32 store index: ((jt2*8+jq)*256 + M)*2 + (jp&1); wave = full 256B line
    const size_t sidx32 = ((size_t)(jt2 * 8 + jq) * 256 + M) * 2 + (jp & 1);

    __syncthreads();   // Wlds visible

    unsigned int* mycnt = cnt + gm * 32;       // [0]=barrier [1]=xcd mask [2]=arrive
    const int ml = q * 4;                      // local row base within 16-row tile

    // --- shared spin budget (tid==0 only): hang-proofing. Healthy usage is
    //     ~20-50k iters across the whole run; 1M = 20-50x headroom (~28 ms). ---
    unsigned spin_budget = 1u << 20;

    // --- XCD-uniformity detection (device-scope, once). Bailout -> SAFE. ---
    if (tid == 0) {
        unsigned myxcd;
        asm volatile("s_getreg_b32 %0, hwreg(HW_REG_XCC_ID)" : "=s"(myxcd));
        __hip_atomic_fetch_or(mycnt + 1, 1u << (myxcd & 31u),
                              __ATOMIC_RELAXED, __HIP_MEMORY_SCOPE_AGENT);
        __hip_atomic_fetch_add(mycnt + 2, 1u,
                               __ATOMIC_RELAXED, __HIP_MEMORY_SCOPE_AGENT);
        int ok = 0;
        while (spin_budget) {
            if (__hip_atomic_load(mycnt + 2, __ATOMIC_RELAXED,
                                  __HIP_MEMORY_SCOPE_AGENT) >= 32u) { ok = 1; break; }
            __builtin_amdgcn_s_sleep(1);
            --spin_budget;
        }
        unsigned mm = __hip_atomic_load(mycnt + 1, __ATOMIC_RELAXED,
                                        __HIP_MEMORY_SCOPE_AGENT);
        ((volatile int*)scr)[0] = (ok && ((mm & (mm - 1u)) == 0u)) ? 1 : 0;
    }
    __syncthreads();
    const bool fastmode = (((volatile int*)scr)[0] != 0);
    __syncthreads();   // everyone captured the flag before scr is reused

    auto mainloop = [&](auto FASTC) {
        constexpr bool FAST = decltype(FASTC)::value;
        for (int t = 0; t < TT; ++t) {
            const unsigned long long* hR = hbase + (size_t)(t & 1) * HP_U64;
            unsigned long long* hW = hbase + (size_t)((t + 1) & 1) * HP_U64;

            // prefetch y_hist x (consumed in epilogue; hides under K-loop)
            float x = y_hist[(size_t)M * TT + t];

            float4v acc[8] = {{0.f,0.f,0.f,0.f},{0.f,0.f,0.f,0.f},{0.f,0.f,0.f,0.f},
                              {0.f,0.f,0.f,0.f},{0.f,0.f,0.f,0.f},{0.f,0.f,0.f,0.f},
                              {0.f,0.f,0.f,0.f},{0.f,0.f,0.f,0.f}};

            // --- sync-free K-loop: 8 chunks of K=32, FULL 8-deep prefetch ring ---
            unsigned long long ring[8][2];
            if constexpr (FAST) {
                // sc1: device scope — probes the (same-XCD) L2, hits dirty
                // lines from fastmode stores; bypasses possibly-stale L1.
#pragma unroll
                for (int p = 0; p < 8; ++p) {
                    size_t ua = (size_t)(k4 * 8 + p) * 2048 + qoff + abase;
                    asm volatile("global_load_dwordx2 %0, %1, off sc1"
                                 : "=v"(ring[p][0]) : "v"(&hR[ua]));
                    asm volatile("global_load_dwordx2 %0, %1, off sc1"
                                 : "=v"(ring[p][1]) : "v"(&hR[ua + 256]));
                }
                asm volatile("s_waitcnt vmcnt(0)" ::: "memory");
                __builtin_amdgcn_sched_barrier(0);   // rule #18: pin uses after wait
            } else {
#pragma unroll
                for (int p = 0; p < 8; ++p) {
                    size_t ua = (size_t)(k4 * 8 + p) * 2048 + qoff + abase;
                    ring[p][0] = __hip_atomic_load((unsigned long long*)&hR[ua],
                                                   __ATOMIC_RELAXED, __HIP_MEMORY_SCOPE_AGENT);
                    ring[p][1] = __hip_atomic_load((unsigned long long*)&hR[ua + 256],
                                                   __ATOMIC_RELAXED, __HIP_MEMORY_SCOPE_AGENT);
                }
            }
#pragma unroll
            for (int ch = 0; ch < 8; ++ch) {
                union { unsigned long long u[2]; half8 h; } af;
                af.u[0] = ring[ch][0];
                af.u[1] = ring[ch][1];
                const int kc = k4 * 8 + ch;
#pragma unroll
                for (int g = 0; g < 2; ++g)
#pragma unroll
                    for (int nt = 0; nt < 2; ++nt) {
                        half8 bh = *(const half8*)
                            &Wlds[(size_t)((kc * 2 + g) * 128 + nt * 64 + lane) * 8];
                        acc[g * 2 + nt] =
                            __builtin_amdgcn_mfma_f32_16x16x32_f16(af.h, bh, acc[g * 2 + nt], 0, 0, 0);
                    }
#pragma unroll
                for (int g2 = 0; g2 < 2; ++g2)
#pragma unroll
                    for (int nt = 0; nt < 2; ++nt)
                        acc[(2 + g2) * 2 + nt] =
                            __builtin_amdgcn_mfma_f32_16x16x32_f16(af.h, Breg[ch][g2][nt],
                                                                   acc[(2 + g2) * 2 + nt], 0, 0, 0);
            }

            // --- 4-way k-reduction, 2 rounds in 32 KB scratch (v6-proven) ---
            if (k4 >= 2) {
                int rb = (m2 * 2 + (k4 & 1)) * 2048;
#pragma unroll
                for (int a = 0; a < 8; ++a) {
                    int n = (a >> 1) * 32 + (a & 1) * 16 + (lane & 15);
                    *(float4v*)&scr[rb + n * 16 + (ml ^ ((n & 3) << 2))] = acc[a];
                }
            }
            __syncthreads();
            if (k4 < 2) {
                int rb = (m2 * 2 + k4) * 2048;
#pragma unroll
                for (int a = 0; a < 8; ++a) {
                    int n = (a >> 1) * 32 + (a & 1) * 16 + (lane & 15);
                    acc[a] += *(const float4v*)&scr[rb + n * 16 + (ml ^ ((n & 3) << 2))];
                }
                if (k4 == 1) {
#pragma unroll
                    for (int a = 0; a < 8; ++a) {
                        int n = (a >> 1) * 32 + (a & 1) * 16 + (lane & 15);
                        *(float4v*)&scr[(m2 * 2 + 1) * 2048 + n * 16 + (ml ^ ((n & 3) << 2))] = acc[a];
                    }
                }
            }
            __syncthreads();
            if (k4 == 0) {
#pragma unroll
                for (int a = 0; a < 8; ++a) {
                    int n = (a >> 1) * 32 + (a & 1) * 16 + (lane & 15);
                    int sw = n * 16 + (ml ^ ((n & 3) << 2));
                    acc[a] += *(const float4v*)&scr[(m2 * 2 + 1) * 2048 + sw];
                    *(float4v*)&scr[(m2 * 2) * 2048 + sw] = acc[a];
                }
            }
            __syncthreads();

            // --- epilogue (all 512 threads): 1 row x 2 j; one u32 store ---
            {
                int rbase = (em >> 4) * 2 * 2048;
                union { _Float16 h[2]; unsigned int u; } hv;
#pragma unroll
                for (int jj = 0; jj < 2; ++jj) {
                    int jl = jp * 2 + jj;                      // 0..31
                    int msw = (em & 15) ^ ((jl & 3) << 2);
                    float gi = scr[rbase + (0 * 32 + jl) * 16 + msw] + x * wi_[0][jj] + bs_[0][jj];
                    float gf = scr[rbase + (1 * 32 + jl) * 16 + msw] + x * wi_[1][jj] + bs_[1][jj];
                    float gg = scr[rbase + (2 * 32 + jl) * 16 + msw] + x * wi_[2][jj] + bs_[2][jj];
                    float go = scr[rbase + (3 * 32 + jl) * 16 + msw] + x * wi_[3][jj] + bs_[3][jj];
                    float cn = sigf(gf) * c_[jj] + sigf(gi) * tanhff(gg);
                    float hn = sigf(go) * tanhff(cn);
                    c_[jj] = cn;
                    hv.h[jj] = (_Float16)hn;
                }
                if constexpr (FAST)
                    asm volatile("global_store_dword %0, %1, off sc0"
                                 : : "v"((void*)((unsigned int*)hW + sidx32)), "v"(hv.u) : "memory");
                else
                    asm volatile("global_store_dword %0, %1, off sc0 sc1"
                                 : : "v"((void*)((unsigned int*)hW + sidx32)), "v"(hv.u) : "memory");
            }

            // --- drain stores, then m-group barrier (32 WGs, budget-bounded) ---
            asm volatile("s_waitcnt vmcnt(0)" ::: "memory");
            __syncthreads();
            if (tid == 0) {
                unsigned target = 32u * (unsigned)(t + 1);
                if constexpr (FAST) {
                    // add is a workgroup-scope RMW (executes at the local L2 —
                    // the group's single L2 in fastmode); poll is an agent
                    // atomic load probing that same L2.
                    __hip_atomic_fetch_add(mycnt, 1u, __ATOMIC_RELAXED,
                                           __HIP_MEMORY_SCOPE_WORKGROUP);
                    while (spin_budget &&
                           __hip_atomic_load(mycnt, __ATOMIC_RELAXED,
                                             __HIP_MEMORY_SCOPE_AGENT) < target) {
                        __builtin_amdgcn_s_sleep(1);
                        --spin_budget;
                    }
                } else {
                    __hip_atomic_fetch_add(mycnt, 1u, __ATOMIC_RELAXED,
                                           __HIP_MEMORY_SCOPE_AGENT);
                    while (spin_budget &&
                           __hip_atomic_load(mycnt, __ATOMIC_RELAXED,
                                             __HIP_MEMORY_SCOPE_AGENT) < target) {
                        __builtin_amdgcn_s_sleep(1);
                        --spin_budget;
                    }
                }
            }
            __syncthreads();
        }
    };
    if (fastmode) mainloop(std::integral_constant<bool, true>{});
    else          mainloop(std::integral_constant<bool, false>{});

    // --- final FC (h final in buffer 0): jt2==0 WGs, k4==0 waves ---
    if (jt2 == 0 && k4 == 0) {
        const unsigned long long* hF = hbase;   // buffer 0
#pragma unroll 1
        for (int rr = 0; rr < 16; ++rr) {
            int row = gm * 32 + m2 * 16 + rr;
            int boff = row;                     // boff == M
            float s = 0.f;
#pragma unroll 1
            for (int uu = 0; uu < 4; ++uu) {
                int U = uu * 64 + lane;
                unsigned long long u;
                if (fastmode) {
                    asm volatile("global_load_dwordx2 %0, %1, off sc1\n\ts_waitcnt vmcnt(0)"
                                 : "=v"(u) : "v"(&hF[(size_t)U * 256 + boff]) : "memory");
                } else {
                    u = __hip_atomic_load((unsigned long long*)&hF[(size_t)U * 256 + boff],
                                          __ATOMIC_RELAXED, __HIP_MEMORY_SCOPE_AGENT);
                }
                int kb = (U >> 3) * 32 + ((U >> 1) & 3) * 8 + (U & 1) * 4;
                union { _Float16 h[4]; unsigned long long x; } v;
                v.x = u;
                float4 wf = *(const float4*)(W_fc + kb);
                s += (float)v.h[0] * wf.x + (float)v.h[1] * wf.y +
                     (float)v.h[2] * wf.z + (float)v.h[3] * wf.w;
            }
#pragma unroll
            for (int off = 32; off > 0; off >>= 1) s += __shfl_xor(s, off);
            if (lane == 0) out[row] = s + b_fc[0];
        }
    }
}

extern "C" void kernel_launch(void* const* d_in, const int* in_sizes, int n_in,
                              void* d_out, int out_size, void* d_ws, size_t ws_size,
                              hipStream_t stream) {
    const float* y_hist = (const float*)d_in[0];
    const float* W_ih   = (const float*)d_in[1];
    const float* W_hh   = (const float*)d_in[2];
    const float* b_ih   = (const float*)d_in[3];
    const float* b_hh   = (const float*)d_in[4];
    const float* W_fc   = (const float*)d_in[5];
    const float* b_fc   = (const float*)d_in[6];
    const float* h0     = (const float*)d_in[7];
    const float* c0     = (const float*)d_in[8];
    float* out = (float*)d_out;

    // ws: Wp fp16 (8 MB) | h buffers 2 x 512 KB | cnt (1 KB)
    unsigned short* Wp = (unsigned short*)d_ws;
    unsigned long long* hbase = (unsigned long long*)(Wp + (size_t)4194304);
    unsigned int* cnt = (unsigned int*)(hbase + 2 * HP_U64);

    pack_w<<<2048, 256, 0, stream>>>(W_hh, Wp);
    prep_state<<<256, 256, 0, stream>>>(h0, hbase, cnt);

    // 256 WGs x 512 threads, 160 KiB LDS -> 1 WG/CU, all co-resident
    lstm_persist<<<256, 512, 0, stream>>>(y_hist, W_ih, b_ih, b_hh, c0, W_fc, b_fc,
                                          Wp, hbase, cnt, out);
}